// Round 10
// baseline (229.186 us; speedup 1.0000x reference)
//
#include <hip/hip_runtime.h>
#include <stdint.h>

#define B_    2
#define CIN   128
#define HIMG  32
#define WIMG  32
#define COUT_ 128
#define PP    1024
#define FTOT  1152
#define NSUB  9
#define NS    8
#define NT    8
#define NROW  18

typedef int v4i __attribute__((ext_vector_type(4)));

// ws layout (bytes) — r7 proved ws_size >= 5017600 (wby path ran there)
#define OFF_NORM   0                      // 128 f32
#define OFF_MAXV   512                    // 18 u32
#define OFF_MB     640                    // 18 uint2 (m, b)
#define OFF_PMODE  800                    // 18 i32
#define OFF_LUT    1024                   // 18*132 u8 (fallback gather table)
#define OFF_XQ     4096                   // 2*1024*1152 u8 = 2359296
#define OFF_WBY    2363392                // 144 planes * 16384 = 2359296 (16B aligned)

// Extract bit `sh` of each packed byte -> 0/1 bytes (i8 MFMA fragment).
__device__ __forceinline__ v4i bitsel(uint4 d, int sh) {
    v4i r;
    r[0] = (int)((d.x >> sh) & 0x01010101u);
    r[1] = (int)((d.y >> sh) & 0x01010101u);
    r[2] = (int)((d.z >> sh) & 0x01010101u);
    r[3] = (int)((d.w >> sh) & 0x01010101u);
    return r;
}

// ---------------------------------------------------------------------------
// Weight prep: per-o norm, f64 quantization (matches np-f64 golden), then
// expand bit-planes to 0/1 bytes in MFMA A-frag layout:
// wby[(sub*8+t)*2+sign][o][k]  (plane stride 16384 = 128 o x 128 k).
// ---------------------------------------------------------------------------
__global__ __launch_bounds__(256) void k_prep_w(const float* __restrict__ w,
                                                float* __restrict__ norm_out,
                                                uint8_t* __restrict__ wby) {
    int o = blockIdx.x, tid = threadIdx.x;
    __shared__ float red[256];
    __shared__ alignas(16) uint8_t sip[FTOT];
    __shared__ alignas(16) uint8_t sin_[FTOT];
    const float* wo = w + (size_t)o * FTOT;
    float m = 0.f;
    for (int f = tid; f < FTOT; f += 256) m = fmaxf(m, fabsf(wo[f]));
    red[tid] = m;
    __syncthreads();
    for (int s2 = 128; s2 > 0; s2 >>= 1) {
        if (tid < s2) red[tid] = fmaxf(red[tid], red[tid + s2]);
        __syncthreads();
    }
    float norm = red[0];
    if (tid == 0) norm_out[o] = norm;
    for (int f = tid; f < FTOT; f += 256) {
        double wi = rint(((double)wo[f] / (double)norm) * 255.0);
        sip[f] = (uint8_t)(int)fmax(wi, 0.0);
        sin_[f] = (uint8_t)(int)fmax(-wi, 0.0);
    }
    __syncthreads();
    // e -> (sub, t, sign, q4): one 16B plane segment per iteration
    for (int e = tid; e < 1152; e += 256) {
        int q4 = e & 7, ts = (e >> 3) & 15, sub = e >> 7;
        int sign = ts & 1, t = ts >> 1;
        const uint8_t* src = (sign ? sin_ : sip) + sub * 128 + q4 * 16;
        uint4 d = *(const uint4*)src;
        *(v4i*)(wby + (size_t)(((sub * 8 + t) * 2 + sign) * 16384)
                    + o * 128 + q4 * 16) = bitsel(d, t);
    }
}

// ---------------------------------------------------------------------------
// Input prep (proven): im2col + quantize to u8 xq[b][p][f]; zero maxv.
// ---------------------------------------------------------------------------
__global__ __launch_bounds__(256) void k_prep_x(const float* __restrict__ x,
                                                uint8_t* __restrict__ xq,
                                                uint32_t* __restrict__ maxv) {
    if (blockIdx.x == 0 && threadIdx.x < NROW) maxv[threadIdx.x] = 0u;
    int gid = blockIdx.x * 256 + threadIdx.x;    // 2*1024*72 = 147456 exact
    int fg = gid % 72;
    int rest = gid / 72;
    int p = rest & 1023;
    int b = rest >> 10;
    int py = p >> 5, px = p & 31;
    uint32_t dw[4] = {0, 0, 0, 0};
    #pragma unroll
    for (int j = 0; j < 16; ++j) {
        int f = fg * 16 + j;
        int c = f / 9, u = f % 9;
        int kh = u / 3, kw = u % 3;
        int y = py + kh - 1, xx = px + kw - 1;
        uint32_t xi = 0;
        if (y >= 0 && y < HIMG && xx >= 0 && xx < WIMG) {
            float v = x[(((size_t)b * CIN + c) * HIMG + y) * WIMG + xx];
            float q = rintf(v * 256.0f);              // exact: power-of-2 scale
            q = fminf(fmaxf(q, 0.f), 255.f);
            xi = (uint32_t)q;
        }
        dw[j >> 2] |= xi << ((j & 3) * 8);
    }
    *reinterpret_cast<uint4*>(xq + (size_t)((b << 10) + p) * FTOT + fg * 16) =
        make_uint4(dw[0], dw[1], dw[2], dw[3]);
}

// ---------------------------------------------------------------------------
// Pass 1: max pr per (sub, sign). Block(512)=(b,ot,pt).
// wave wid = (s-half sh = wid>>2, t-pair tp = wid&3): covers 4s x 2t x 2sign.
// W-frags: 8 batched dwordx4 per sub from wby (register-resident, no LDS).
// ---------------------------------------------------------------------------
__global__ __launch_bounds__(512, 4) void k_max(const uint8_t* __restrict__ xq,
                                                const uint8_t* __restrict__ wby,
                                                uint32_t* __restrict__ maxv) {
    int tid = threadIdx.x, lane = tid & 63, wid = tid >> 6;
    int blk = blockIdx.x;
    int b = blk >> 9, r = blk & 511, ot = r >> 6, pt = r & 63;
    int tp = wid & 3, sh = wid >> 2;
    int col = lane & 15, kq = lane >> 4;
    int p = pt * 16 + col, oa = ot * 16 + col;
    __shared__ uint32_t smax[8][NSUB][2];

    const uint8_t* xbase = xq + (size_t)((b << 10) + p) * FTOT + kq * 16;
    // plane index = sub*16 + (tp*2+tt)*2 + sign ; per-sub stride 262144
    const uint8_t* wbase = wby + (size_t)(tp * 2 * 2) * 16384 + oa * 128 + kq * 16;

    for (int sub = 0; sub < NSUB; ++sub) {
        const uint8_t* wb = wbase + (size_t)sub * 262144;
        v4i wf[8];
        #pragma unroll
        for (int j = 0; j < 4; ++j) {                 // j = tt*2+sign
            wf[j * 2]     = *(const v4i*)(wb + j * 16384);
            wf[j * 2 + 1] = *(const v4i*)(wb + j * 16384 + 64);
        }
        uint4 xg0 = *(const uint4*)(xbase + sub * 128);
        uint4 xg1 = *(const uint4*)(xbase + sub * 128 + 64);

        int mp = 0, mn = 0;
        #pragma unroll
        for (int si = 0; si < 4; ++si) {
            int s = sh * 4 + si;
            v4i bf0 = bitsel(xg0, s), bf1 = bitsel(xg1, s);
            #pragma unroll
            for (int tt = 0; tt < 2; ++tt) {
                v4i acc = {0, 0, 0, 0};
                acc = __builtin_amdgcn_mfma_i32_16x16x64_i8(wf[tt * 4 + 0], bf0, acc, 0, 0, 0);
                acc = __builtin_amdgcn_mfma_i32_16x16x64_i8(wf[tt * 4 + 1], bf1, acc, 0, 0, 0);
                mp = max(mp, max(max(acc[0], acc[1]), max(acc[2], acc[3])));
                v4i acn = {0, 0, 0, 0};
                acn = __builtin_amdgcn_mfma_i32_16x16x64_i8(wf[tt * 4 + 2], bf0, acn, 0, 0, 0);
                acn = __builtin_amdgcn_mfma_i32_16x16x64_i8(wf[tt * 4 + 3], bf1, acn, 0, 0, 0);
                mn = max(mn, max(max(acn[0], acn[1]), max(acn[2], acn[3])));
            }
        }
        #pragma unroll
        for (int off = 32; off > 0; off >>= 1) {
            mp = max(mp, __shfl_xor(mp, off));
            mn = max(mn, __shfl_xor(mn, off));
        }
        if (lane == 0) { smax[wid][sub][0] = (uint32_t)mp; smax[wid][sub][1] = (uint32_t)mn; }
    }
    __syncthreads();
    if (tid < NROW) {
        int sub = tid >> 1, sg = tid & 1;
        uint32_t m = 0;
        #pragma unroll
        for (int w2 = 0; w2 < 8; ++w2) m = max(m, smax[w2][sub][sg]);
        atomicMax(&maxv[tid], m);
    }
}

// ---------------------------------------------------------------------------
// k_lut (proven): exact f64 table; integer (m,b) feasibility search with
// floor((pr*m+b)/2^16) == code(pr) for all pr<=vmax; fallback global LUT.
// ---------------------------------------------------------------------------
__global__ __launch_bounds__(256) void k_lut(const uint32_t* __restrict__ maxv,
                                             uint8_t* __restrict__ lut,
                                             uint2* __restrict__ mb,
                                             int* __restrict__ pmode) {
    int row = blockIdx.x, tid = threadIdx.x;
    __shared__ uint8_t codes[132];
    __shared__ int bestm;
    if (tid == 0) bestm = 0x7fffffff;
    int vmax = (int)maxv[row];
    for (int pr = tid; pr < 129; pr += 256) {
        double vmaxd = fmax((double)vmax, 1e-6);
        double step = vmaxd / 15.0;
        double q = rint((double)pr / step);
        q = fmin(fmax(q, 0.0), 15.0);
        codes[pr] = (uint8_t)q;
        lut[row * 132 + pr] = (uint8_t)q;
    }
    __syncthreads();
    int ve = max(vmax, 1);
    int m0 = (983040 + ve / 2) / ve;           // ~2^16*15/vmax
    int m = m0 - 128 + tid;
    if (m >= 1) {
        int L = 0, U = 0x7fffffff;
        for (int pr = 0; pr <= vmax && pr <= 128; ++pr) {
            int c = codes[pr];
            int lo = (c << 16) - pr * m;
            int hi = ((c + 1) << 16) - 1 - pr * m;
            L = max(L, lo);
            U = min(U, hi);
            if (L > U) break;
        }
        if (L <= U) atomicMin(&bestm, m);
    }
    __syncthreads();
    if (tid == 0) {
        if (bestm == 0x7fffffff) {
            pmode[row] = 1;
            mb[row] = make_uint2(0u, 0u);
        } else {
            int L = 0;
            for (int pr = 0; pr <= vmax && pr <= 128; ++pr)
                L = max(L, ((int)codes[pr] << 16) - pr * bestm);
            pmode[row] = 0;
            mb[row] = make_uint2((uint32_t)bestm, (uint32_t)L);
        }
    }
}

// ---------------------------------------------------------------------------
// Pass 2: same wave structure; int-mad ADC (3 VALU/pr, exact); integer
// weighted sums; f64 final scale. LDS only in epilogue reduce.
// ---------------------------------------------------------------------------
__global__ __launch_bounds__(512, 4) void k_adc(const uint8_t* __restrict__ xq,
                                                const uint8_t* __restrict__ wby,
                                                const uint32_t* __restrict__ maxv,
                                                const uint8_t* __restrict__ lut,
                                                const uint2* __restrict__ mb,
                                                const int* __restrict__ pmode,
                                                const float* __restrict__ norm,
                                                float* __restrict__ out) {
    int tid = threadIdx.x, lane = tid & 63, wid = tid >> 6;
    int blk = blockIdx.x;
    int b = blk >> 9, r = blk & 511, ot = r >> 6, pt = r & 63;
    int tp = wid & 3, sh = wid >> 2;
    int col = lane & 15, kq = lane >> 4;
    int p = pt * 16 + col, oa = ot * 16 + col;

    __shared__ int lred[8][64][4];

    const uint8_t* xbase = xq + (size_t)((b << 10) + p) * FTOT + kq * 16;
    const uint8_t* wbase = wby + (size_t)(tp * 2 * 2) * 16384 + oa * 128 + kq * 16;

    int run[4] = {0, 0, 0, 0};
    for (int sub = 0; sub < NSUB; ++sub) {
        const uint8_t* wb = wbase + (size_t)sub * 262144;
        v4i wf[8];
        #pragma unroll
        for (int j = 0; j < 4; ++j) {
            wf[j * 2]     = *(const v4i*)(wb + j * 16384);
            wf[j * 2 + 1] = *(const v4i*)(wb + j * 16384 + 64);
        }
        uint4 xg0 = *(const uint4*)(xbase + sub * 128);
        uint4 xg1 = *(const uint4*)(xbase + sub * 128 + 64);

        int rowp = sub * 2, rown = sub * 2 + 1;
        uint2 mbp = mb[rowp], mbn = mb[rown];
        int fbp = pmode[rowp], fbn = pmode[rown];
        const uint8_t* glp = lut + rowp * 132;
        const uint8_t* gln = lut + rown * 132;
        int vp = (int)maxv[rowp], vn = (int)maxv[rown];

        uint32_t Sp[4] = {0, 0, 0, 0}, Sn[4] = {0, 0, 0, 0};
        #pragma unroll
        for (int si = 0; si < 4; ++si) {
            int s = sh * 4 + si;
            v4i bf0 = bitsel(xg0, s), bf1 = bitsel(xg1, s);
            #pragma unroll
            for (int tt = 0; tt < 2; ++tt) {
                int st = s + tp * 2 + tt;
                v4i acc = {0, 0, 0, 0};
                acc = __builtin_amdgcn_mfma_i32_16x16x64_i8(wf[tt * 4 + 0], bf0, acc, 0, 0, 0);
                acc = __builtin_amdgcn_mfma_i32_16x16x64_i8(wf[tt * 4 + 1], bf1, acc, 0, 0, 0);
                if (fbp == 0) {
                    #pragma unroll
                    for (int i = 0; i < 4; ++i) {
                        uint32_t q = ((__umul24((uint32_t)acc[i], mbp.x) + mbp.y) >> 16) & 15u;
                        Sp[i] += q << st;
                    }
                } else {
                    #pragma unroll
                    for (int i = 0; i < 4; ++i) Sp[i] += (uint32_t)glp[acc[i]] << st;
                }
                v4i acn = {0, 0, 0, 0};
                acn = __builtin_amdgcn_mfma_i32_16x16x64_i8(wf[tt * 4 + 2], bf0, acn, 0, 0, 0);
                acn = __builtin_amdgcn_mfma_i32_16x16x64_i8(wf[tt * 4 + 3], bf1, acn, 0, 0, 0);
                if (fbn == 0) {
                    #pragma unroll
                    for (int i = 0; i < 4; ++i) {
                        uint32_t q = ((__umul24((uint32_t)acn[i], mbn.x) + mbn.y) >> 16) & 15u;
                        Sn[i] += q << st;
                    }
                } else {
                    #pragma unroll
                    for (int i = 0; i < 4; ++i) Sn[i] += (uint32_t)gln[acn[i]] << st;
                }
            }
        }
        // exact: Sp <= 15*240*192 = 691200 < 2^20; vp*Sp < 2^27; 9-sub < 2^31
        #pragma unroll
        for (int i = 0; i < 4; ++i)
            run[i] += vp * (int)Sp[i] - vn * (int)Sn[i];
    }
    #pragma unroll
    for (int i = 0; i < 4; ++i) lred[wid][lane][i] = run[i];
    __syncthreads();
    if (tid < 256) {
        int lane2 = tid >> 2, i = tid & 3;
        long long s64 = 0;
        #pragma unroll
        for (int w2 = 0; w2 < 8; ++w2) s64 += (long long)lred[w2][lane2][i];
        int o = ot * 16 + (lane2 >> 4) * 4 + i;      // C/D: row=(lane>>4)*4+reg [m89]
        int pp2 = pt * 16 + (lane2 & 15);            // C/D: col=lane&15
        double v = (double)s64 * (double)norm[o] / 15.0 / 255.0 / 256.0;
        out[((size_t)(b * COUT_ + o)) * PP + pp2] = (float)v;
    }
    if (blk == 0 && tid == 0) out[(size_t)B_ * COUT_ * PP] = 0.0f;   // adc_loss
}

// ---------------------------------------------------------------------------
extern "C" void kernel_launch(void* const* d_in, const int* in_sizes, int n_in,
                              void* d_out, int out_size, void* d_ws, size_t ws_size,
                              hipStream_t stream) {
    const float* x = (const float*)d_in[0];
    const float* w = (const float*)d_in[1];
    float* out = (float*)d_out;
    char* ws = (char*)d_ws;

    float* norm = (float*)(ws + OFF_NORM);
    uint32_t* maxv = (uint32_t*)(ws + OFF_MAXV);
    uint2* mb = (uint2*)(ws + OFF_MB);
    int* pmode = (int*)(ws + OFF_PMODE);
    uint8_t* lut = (uint8_t*)(ws + OFF_LUT);
    uint8_t* xq  = (uint8_t*)(ws + OFF_XQ);
    uint8_t* wby = (uint8_t*)(ws + OFF_WBY);

    k_prep_w<<<128, 256, 0, stream>>>(w, norm, wby);
    k_prep_x<<<576, 256, 0, stream>>>(x, xq, maxv);
    k_max<<<1024, 512, 0, stream>>>(xq, wby, maxv);
    k_lut<<<NROW, 256, 0, stream>>>(maxv, lut, mb, pmode);
    k_adc<<<1024, 512, 0, stream>>>(xq, wby, maxv, lut, mb, pmode, norm, out);
}

// Round 11
// 170.943 us; speedup vs baseline: 1.3407x; 1.3407x over previous
//
#include <hip/hip_runtime.h>
#include <stdint.h>

#define B_    2
#define CIN   128
#define HIMG  32
#define WIMG  32
#define COUT_ 128
#define PP    1024
#define FTOT  1152
#define NSUB  9
#define NS    8
#define NT    8
#define NROW  18

typedef int v4i __attribute__((ext_vector_type(4)));

// ws layout (bytes) — 2.66 MB proven footprint
#define OFF_NORM   0                      // 128 f32
#define OFF_MAXV   512                    // 18 u32
#define OFF_MB     640                    // 18 uint2 (m, b)
#define OFF_PMODE  800                    // 18 i32
#define OFF_LUT    1024                   // 18*132 u8 (fallback gather table)
#define OFF_WQP    4096                   // 128*1152 u8 (packed magnitudes)
#define OFF_WQN    (4096 + 147456)
#define OFF_XQ     (4096 + 2*147456)      // 2*1024*1152 u8

// ---------------------------------------------------------------------------
// Weight prep (proven): per-o norm, f64 quantization, |wi| u8 per sign.
// ---------------------------------------------------------------------------
__global__ __launch_bounds__(256) void k_prep_w(const float* __restrict__ w,
                                                float* __restrict__ norm_out,
                                                uint8_t* __restrict__ wqp,
                                                uint8_t* __restrict__ wqn) {
    int o = blockIdx.x, tid = threadIdx.x;
    __shared__ float red[256];
    const float* wo = w + (size_t)o * FTOT;
    float m = 0.f;
    for (int f = tid; f < FTOT; f += 256) m = fmaxf(m, fabsf(wo[f]));
    red[tid] = m;
    __syncthreads();
    for (int s2 = 128; s2 > 0; s2 >>= 1) {
        if (tid < s2) red[tid] = fmaxf(red[tid], red[tid + s2]);
        __syncthreads();
    }
    float norm = red[0];
    if (tid == 0) norm_out[o] = norm;
    for (int f = tid; f < FTOT; f += 256) {
        double wi = rint(((double)wo[f] / (double)norm) * 255.0);
        wqp[(size_t)o * FTOT + f] = (uint8_t)(int)fmax(wi, 0.0);
        wqn[(size_t)o * FTOT + f] = (uint8_t)(int)fmax(-wi, 0.0);
    }
}

// ---------------------------------------------------------------------------
// Input prep (proven): im2col + quantize to u8 xq[b][p][f]; zero maxv.
// ---------------------------------------------------------------------------
__global__ __launch_bounds__(256) void k_prep_x(const float* __restrict__ x,
                                                uint8_t* __restrict__ xq,
                                                uint32_t* __restrict__ maxv) {
    if (blockIdx.x == 0 && threadIdx.x < NROW) maxv[threadIdx.x] = 0u;
    int gid = blockIdx.x * 256 + threadIdx.x;    // 2*1024*72 = 147456 exact
    int fg = gid % 72;
    int rest = gid / 72;
    int p = rest & 1023;
    int b = rest >> 10;
    int py = p >> 5, px = p & 31;
    uint32_t dw[4] = {0, 0, 0, 0};
    #pragma unroll
    for (int j = 0; j < 16; ++j) {
        int f = fg * 16 + j;
        int c = f / 9, u = f % 9;
        int kh = u / 3, kw = u % 3;
        int y = py + kh - 1, xx = px + kw - 1;
        uint32_t xi = 0;
        if (y >= 0 && y < HIMG && xx >= 0 && xx < WIMG) {
            float v = x[(((size_t)b * CIN + c) * HIMG + y) * WIMG + xx];
            float q = rintf(v * 256.0f);              // exact: power-of-2 scale
            q = fminf(fmaxf(q, 0.f), 255.f);
            xi = (uint32_t)q;
        }
        dw[j >> 2] |= xi << ((j & 3) * 8);
    }
    *reinterpret_cast<uint4*>(xq + (size_t)((b << 10) + p) * FTOT + fg * 16) =
        make_uint4(dw[0], dw[1], dw[2], dw[3]);
}

// Extract bit `sh` of each packed byte -> 0/1 bytes (i8 MFMA fragment).
__device__ __forceinline__ v4i bitsel(uint4 d, int sh) {
    v4i r;
    r[0] = (int)((d.x >> sh) & 0x01010101u);
    r[1] = (int)((d.y >> sh) & 0x01010101u);
    r[2] = (int)((d.z >> sh) & 0x01010101u);
    r[3] = (int)((d.w >> sh) & 0x01010101u);
    return r;
}

// ---------------------------------------------------------------------------
// Pass 1: max pr per (sub, sign). Block(512)=(b,ot,pt), wave = t.
// launch_bounds(512,2): register budget ~256 so w-frags stay resident
// (the 106us r8 run was compiler remat at VGPR 44, not true pressure).
// ---------------------------------------------------------------------------
__global__ __launch_bounds__(512, 2) void k_max(const uint8_t* __restrict__ xq,
                                                const uint8_t* __restrict__ wqp,
                                                const uint8_t* __restrict__ wqn,
                                                uint32_t* __restrict__ maxv) {
    int tid = threadIdx.x, lane = tid & 63, wid = tid >> 6;
    int blk = blockIdx.x;
    int b = blk >> 9, r = blk & 511, ot = r >> 6, pt = r & 63;
    int t = wid;
    int col = lane & 15, kq = lane >> 4;
    int p = pt * 16 + col, oa = ot * 16 + col;
    __shared__ uint32_t smax[8][NSUB][2];

    const uint8_t* xbase = xq + (size_t)((b << 10) + p) * FTOT + kq * 16;
    const uint8_t* wpb = wqp + (size_t)oa * FTOT + kq * 16;
    const uint8_t* wnb = wqn + (size_t)oa * FTOT + kq * 16;

    for (int sub = 0; sub < NSUB; ++sub) {
        int fo = sub * 128;
        uint4 wp0 = *(const uint4*)(wpb + fo), wp1 = *(const uint4*)(wpb + fo + 64);
        uint4 wn0 = *(const uint4*)(wnb + fo), wn1 = *(const uint4*)(wnb + fo + 64);
        v4i ap0 = bitsel(wp0, t), ap1 = bitsel(wp1, t);
        v4i an0 = bitsel(wn0, t), an1 = bitsel(wn1, t);
        uint4 xg0 = *(const uint4*)(xbase + fo);
        uint4 xg1 = *(const uint4*)(xbase + fo + 64);

        int mp = 0, mn = 0;
        #pragma unroll
        for (int s = 0; s < NS; ++s) {
            v4i bf0 = bitsel(xg0, s), bf1 = bitsel(xg1, s);
            v4i acc = {0, 0, 0, 0};
            acc = __builtin_amdgcn_mfma_i32_16x16x64_i8(ap0, bf0, acc, 0, 0, 0);
            acc = __builtin_amdgcn_mfma_i32_16x16x64_i8(ap1, bf1, acc, 0, 0, 0);
            // v_max3-friendly shapes: two 3-input maxes
            mp = max(max(acc[0], acc[1]), mp);
            mp = max(max(acc[2], acc[3]), mp);
            v4i acn = {0, 0, 0, 0};
            acn = __builtin_amdgcn_mfma_i32_16x16x64_i8(an0, bf0, acn, 0, 0, 0);
            acn = __builtin_amdgcn_mfma_i32_16x16x64_i8(an1, bf1, acn, 0, 0, 0);
            mn = max(max(acn[0], acn[1]), mn);
            mn = max(max(acn[2], acn[3]), mn);
        }
        #pragma unroll
        for (int off = 32; off > 0; off >>= 1) {
            mp = max(mp, __shfl_xor(mp, off));
            mn = max(mn, __shfl_xor(mn, off));
        }
        if (lane == 0) { smax[wid][sub][0] = (uint32_t)mp; smax[wid][sub][1] = (uint32_t)mn; }
    }
    __syncthreads();
    if (tid < NROW) {
        int sub = tid >> 1, sg = tid & 1;
        uint32_t m = 0;
        #pragma unroll
        for (int w2 = 0; w2 < 8; ++w2) m = max(m, smax[w2][sub][sg]);
        atomicMax(&maxv[tid], m);
    }
}

// ---------------------------------------------------------------------------
// k_lut (proven): exact f64 table; integer (m,b) feasibility search with
// floor((pr*m+b)/2^16) == code(pr) for all pr<=vmax; fallback global LUT.
// ---------------------------------------------------------------------------
__global__ __launch_bounds__(256) void k_lut(const uint32_t* __restrict__ maxv,
                                             uint8_t* __restrict__ lut,
                                             uint2* __restrict__ mb,
                                             int* __restrict__ pmode) {
    int row = blockIdx.x, tid = threadIdx.x;
    __shared__ uint8_t codes[132];
    __shared__ int bestm;
    if (tid == 0) bestm = 0x7fffffff;
    int vmax = (int)maxv[row];
    for (int pr = tid; pr < 129; pr += 256) {
        double vmaxd = fmax((double)vmax, 1e-6);
        double step = vmaxd / 15.0;
        double q = rint((double)pr / step);
        q = fmin(fmax(q, 0.0), 15.0);
        codes[pr] = (uint8_t)q;
        lut[row * 132 + pr] = (uint8_t)q;
    }
    __syncthreads();
    int ve = max(vmax, 1);
    int m0 = (983040 + ve / 2) / ve;           // ~2^16*15/vmax
    int m = m0 - 128 + tid;
    if (m >= 1) {
        int L = 0, U = 0x7fffffff;
        for (int pr = 0; pr <= vmax && pr <= 128; ++pr) {
            int c = codes[pr];
            int lo = (c << 16) - pr * m;
            int hi = ((c + 1) << 16) - 1 - pr * m;
            L = max(L, lo);
            U = min(U, hi);
            if (L > U) break;
        }
        if (L <= U) atomicMin(&bestm, m);
    }
    __syncthreads();
    if (tid == 0) {
        if (bestm == 0x7fffffff) {
            pmode[row] = 1;
            mb[row] = make_uint2(0u, 0u);
        } else {
            int L = 0;
            for (int pr = 0; pr <= vmax && pr <= 128; ++pr)
                L = max(L, ((int)codes[pr] << 16) - pr * bestm);
            pmode[row] = 0;
            mb[row] = make_uint2((uint32_t)bestm, (uint32_t)L);
        }
    }
}

// ---------------------------------------------------------------------------
// Pass 2: wave = t; ADC = mad_u32_u24 + bfe + lshl_add (3 VALU/pr, exact,
// r8-proven numerics); integer weighted sums; f64 final scale.
// ---------------------------------------------------------------------------
__global__ __launch_bounds__(512, 2) void k_adc(const uint8_t* __restrict__ xq,
                                                const uint8_t* __restrict__ wqp,
                                                const uint8_t* __restrict__ wqn,
                                                const uint32_t* __restrict__ maxv,
                                                const uint8_t* __restrict__ lut,
                                                const uint2* __restrict__ mb,
                                                const int* __restrict__ pmode,
                                                const float* __restrict__ norm,
                                                float* __restrict__ out) {
    int tid = threadIdx.x, lane = tid & 63, wid = tid >> 6;
    int blk = blockIdx.x;
    int b = blk >> 9, r = blk & 511, ot = r >> 6, pt = r & 63;
    int t = wid;
    int col = lane & 15, kq = lane >> 4;
    int p = pt * 16 + col, oa = ot * 16 + col;

    __shared__ int lred[8][64][4];

    const uint8_t* xbase = xq + (size_t)((b << 10) + p) * FTOT + kq * 16;
    const uint8_t* wpb = wqp + (size_t)oa * FTOT + kq * 16;
    const uint8_t* wnb = wqn + (size_t)oa * FTOT + kq * 16;

    int run[4] = {0, 0, 0, 0};
    for (int sub = 0; sub < NSUB; ++sub) {
        int fo = sub * 128;
        uint4 wp0 = *(const uint4*)(wpb + fo), wp1 = *(const uint4*)(wpb + fo + 64);
        uint4 wn0 = *(const uint4*)(wnb + fo), wn1 = *(const uint4*)(wnb + fo + 64);
        v4i ap0 = bitsel(wp0, t), ap1 = bitsel(wp1, t);
        v4i an0 = bitsel(wn0, t), an1 = bitsel(wn1, t);
        uint4 xg0 = *(const uint4*)(xbase + fo);
        uint4 xg1 = *(const uint4*)(xbase + fo + 64);

        int rowp = sub * 2, rown = sub * 2 + 1;
        uint2 mbp = mb[rowp], mbn = mb[rown];
        int fbp = pmode[rowp], fbn = pmode[rown];
        const uint8_t* glp = lut + rowp * 132;
        const uint8_t* gln = lut + rown * 132;
        int vp = (int)maxv[rowp], vn = (int)maxv[rown];

        uint32_t Sp[4] = {0, 0, 0, 0}, Sn[4] = {0, 0, 0, 0};
        #pragma unroll
        for (int s = 0; s < NS; ++s) {
            v4i bf0 = bitsel(xg0, s), bf1 = bitsel(xg1, s);
            v4i acc = {0, 0, 0, 0};
            acc = __builtin_amdgcn_mfma_i32_16x16x64_i8(ap0, bf0, acc, 0, 0, 0);
            acc = __builtin_amdgcn_mfma_i32_16x16x64_i8(ap1, bf1, acc, 0, 0, 0);
            if (fbp == 0) {
                #pragma unroll
                for (int i = 0; i < 4; ++i) {
                    // v_mad_u32_u24 (pr<2^8, m<2^24) + v_bfe_u32 + v_lshl_add
                    uint32_t v = __umul24((uint32_t)acc[i], mbp.x) + mbp.y;
                    Sp[i] += ((v >> 16) & 15u) << s;
                }
            } else {
                #pragma unroll
                for (int i = 0; i < 4; ++i) Sp[i] += (uint32_t)glp[acc[i]] << s;
            }
            v4i acn = {0, 0, 0, 0};
            acn = __builtin_amdgcn_mfma_i32_16x16x64_i8(an0, bf0, acn, 0, 0, 0);
            acn = __builtin_amdgcn_mfma_i32_16x16x64_i8(an1, bf1, acn, 0, 0, 0);
            if (fbn == 0) {
                #pragma unroll
                for (int i = 0; i < 4; ++i) {
                    uint32_t v = __umul24((uint32_t)acn[i], mbn.x) + mbn.y;
                    Sn[i] += ((v >> 16) & 15u) << s;
                }
            } else {
                #pragma unroll
                for (int i = 0; i < 4; ++i) Sn[i] += (uint32_t)gln[acn[i]] << s;
            }
        }
        // exact: Sp,Sn <= 15*255 < 2^12 per-s, summed <<s -> < 2^19;
        // vp*Sp < 2^26; <<t (<=7) < 2^30... 9-sub sum: |d|<2^20*? bounded
        // as in r8 (passed): run fits int32.
        #pragma unroll
        for (int i = 0; i < 4; ++i) {
            int d = (int)__umul24((uint32_t)vp, Sp[i]) - (int)__umul24((uint32_t)vn, Sn[i]);
            run[i] += (int)((uint32_t)d << t);
        }
    }
    #pragma unroll
    for (int i = 0; i < 4; ++i) lred[wid][lane][i] = run[i];
    __syncthreads();
    if (tid < 256) {
        int lane2 = tid >> 2, i = tid & 3;
        long long s64 = 0;
        #pragma unroll
        for (int w2 = 0; w2 < 8; ++w2) s64 += (long long)lred[w2][lane2][i];
        int o = ot * 16 + (lane2 >> 4) * 4 + i;      // C/D: row=(lane>>4)*4+reg [m89]
        int pp2 = pt * 16 + (lane2 & 15);            // C/D: col=lane&15
        double v = (double)s64 * (double)norm[o] / 15.0 / 255.0 / 256.0;
        out[((size_t)(b * COUT_ + o)) * PP + pp2] = (float)v;
    }
    if (blk == 0 && tid == 0) out[(size_t)B_ * COUT_ * PP] = 0.0f;   // adc_loss
}

// ---------------------------------------------------------------------------
extern "C" void kernel_launch(void* const* d_in, const int* in_sizes, int n_in,
                              void* d_out, int out_size, void* d_ws, size_t ws_size,
                              hipStream_t stream) {
    const float* x = (const float*)d_in[0];
    const float* w = (const float*)d_in[1];
    float* out = (float*)d_out;
    char* ws = (char*)d_ws;

    float* norm = (float*)(ws + OFF_NORM);
    uint32_t* maxv = (uint32_t*)(ws + OFF_MAXV);
    uint2* mb = (uint2*)(ws + OFF_MB);
    int* pmode = (int*)(ws + OFF_PMODE);
    uint8_t* lut = (uint8_t*)(ws + OFF_LUT);
    uint8_t* wqp = (uint8_t*)(ws + OFF_WQP);
    uint8_t* wqn = (uint8_t*)(ws + OFF_WQN);
    uint8_t* xq  = (uint8_t*)(ws + OFF_XQ);

    k_prep_w<<<128, 256, 0, stream>>>(w, norm, wqp, wqn);
    k_prep_x<<<576, 256, 0, stream>>>(x, xq, maxv);
    k_max<<<1024, 512, 0, stream>>>(xq, wqp, wqn, maxv);
    k_lut<<<NROW, 256, 0, stream>>>(maxv, lut, mb, pmode);
    k_adc<<<1024, 512, 0, stream>>>(xq, wqp, wqn, maxv, lut, mb, pmode, norm, out);
}

// Round 12
// 140.304 us; speedup vs baseline: 1.6335x; 1.2184x over previous
//
#include <hip/hip_runtime.h>
#include <stdint.h>

#define B_    2
#define CIN   128
#define HIMG  32
#define WIMG  32
#define COUT_ 128
#define PP    1024
#define FTOT  1152
#define NSUB  9
#define NS    8
#define NT    8

typedef int v4i __attribute__((ext_vector_type(4)));

// ws layout (bytes) — total ~2.66 MB (same footprint class as proven rounds)
#define OFF_NORM   0                      // 128 f32
#define OFF_MAXV   512                    // 18 u32
#define OFF_LUT    1024                   // 18*132 u8
#define OFF_WQP    4096                   // 128*1152 u8
#define OFF_WQN    (4096 + 147456)
#define OFF_XQ     (4096 + 2*147456)      // 2*1024*1152 u8

// ---------------------------------------------------------------------------
// Weight prep: per-o norm (f32 max), f64 quantization (matches np-f64 golden),
// store |wi| magnitudes as u8 per sign: wq[o][f].
// ---------------------------------------------------------------------------
__global__ __launch_bounds__(256) void k_prep_w(const float* __restrict__ w,
                                                float* __restrict__ norm_out,
                                                uint8_t* __restrict__ wqp,
                                                uint8_t* __restrict__ wqn) {
    int o = blockIdx.x, tid = threadIdx.x;
    __shared__ float red[256];
    const float* wo = w + (size_t)o * FTOT;
    float m = 0.f;
    for (int f = tid; f < FTOT; f += 256) m = fmaxf(m, fabsf(wo[f]));
    red[tid] = m;
    __syncthreads();
    for (int s2 = 128; s2 > 0; s2 >>= 1) {
        if (tid < s2) red[tid] = fmaxf(red[tid], red[tid + s2]);
        __syncthreads();
    }
    float norm = red[0];
    if (tid == 0) norm_out[o] = norm;
    for (int f = tid; f < FTOT; f += 256) {
        double wi = rint(((double)wo[f] / (double)norm) * 255.0);
        wqp[(size_t)o * FTOT + f] = (uint8_t)(int)fmax(wi, 0.0);
        wqn[(size_t)o * FTOT + f] = (uint8_t)(int)fmax(-wi, 0.0);
    }
}

// ---------------------------------------------------------------------------
// Input prep: im2col + unsigned fixed-point quantize, store xi bytes xq[b][p][f].
// Thread per (b, p, 16-feature group): 16 gathers -> one coalesced 16B store.
// ---------------------------------------------------------------------------
__global__ __launch_bounds__(256) void k_prep_x(const float* __restrict__ x,
                                                uint8_t* __restrict__ xq) {
    int gid = blockIdx.x * 256 + threadIdx.x;    // 2*1024*72 = 147456 exact
    int fg = gid % 72;
    int rest = gid / 72;
    int p = rest & 1023;
    int b = rest >> 10;
    int py = p >> 5, px = p & 31;
    uint32_t dw[4] = {0, 0, 0, 0};
    #pragma unroll
    for (int j = 0; j < 16; ++j) {
        int f = fg * 16 + j;
        int c = f / 9, u = f % 9;
        int kh = u / 3, kw = u % 3;
        int y = py + kh - 1, xx = px + kw - 1;
        uint32_t xi = 0;
        if (y >= 0 && y < HIMG && xx >= 0 && xx < WIMG) {
            float v = x[(((size_t)b * CIN + c) * HIMG + y) * WIMG + xx];
            float q = rintf(v * 256.0f);              // exact: power-of-2 scale
            q = fminf(fmaxf(q, 0.f), 255.f);
            xi = (uint32_t)q;
        }
        dw[j >> 2] |= xi << ((j & 3) * 8);
    }
    *reinterpret_cast<uint4*>(xq + (size_t)((b << 10) + p) * FTOT + fg * 16) =
        make_uint4(dw[0], dw[1], dw[2], dw[3]);
}

// Extract bit `sh` of each packed byte -> 0/1 bytes (i8 MFMA operand fragment).
__device__ __forceinline__ v4i bitsel(uint4 d, int sh) {
    v4i r;
    r[0] = (int)((d.x >> sh) & 0x01010101u);
    r[1] = (int)((d.y >> sh) & 0x01010101u);
    r[2] = (int)((d.z >> sh) & 0x01010101u);
    r[3] = (int)((d.w >> sh) & 0x01010101u);
    return r;
}

// ---------------------------------------------------------------------------
// Pass 1: max pr per (sub, sign) via MFMA. Block(512) = (b,ot,pt), wave = s.
// A = w bits (16 o x 64 k), B = x bits (64 k x 16 p), 2 MFMAs chain K=128.
// ---------------------------------------------------------------------------
__global__ __launch_bounds__(512) void k_max(const uint8_t* __restrict__ xq,
                                             const uint8_t* __restrict__ wqp,
                                             const uint8_t* __restrict__ wqn,
                                             uint32_t* __restrict__ maxv) {
    int tid = threadIdx.x, lane = tid & 63, wid = tid >> 6;
    int blk = blockIdx.x;
    int b = blk >> 9, r = blk & 511, ot = r >> 6, pt = r & 63;
    int s = wid;
    int col = lane & 15, kq = lane >> 4;
    int p = pt * 16 + col, oa = ot * 16 + col;
    __shared__ uint32_t smax[8][NSUB][2];

    const uint8_t* xbase = xq + (size_t)((b << 10) + p) * FTOT + kq * 16;
    const uint8_t* wpb = wqp + (size_t)oa * FTOT + kq * 16;
    const uint8_t* wnb = wqn + (size_t)oa * FTOT + kq * 16;

    for (int sub = 0; sub < NSUB; ++sub) {
        int fo = sub * 128;
        uint4 xg0 = *(const uint4*)(xbase + fo);
        uint4 xg1 = *(const uint4*)(xbase + fo + 64);
        v4i bf0 = bitsel(xg0, s), bf1 = bitsel(xg1, s);
        uint4 wp0 = *(const uint4*)(wpb + fo), wp1 = *(const uint4*)(wpb + fo + 64);
        uint4 wn0 = *(const uint4*)(wnb + fo), wn1 = *(const uint4*)(wnb + fo + 64);
        int mp = 0, mn = 0;
        #pragma unroll
        for (int t = 0; t < NT; ++t) {
            v4i acc = {0, 0, 0, 0};
            acc = __builtin_amdgcn_mfma_i32_16x16x64_i8(bitsel(wp0, t), bf0, acc, 0, 0, 0);
            acc = __builtin_amdgcn_mfma_i32_16x16x64_i8(bitsel(wp1, t), bf1, acc, 0, 0, 0);
            mp = max(max(acc[0], acc[1]), max(max(acc[2], acc[3]), mp));
            v4i acn = {0, 0, 0, 0};
            acn = __builtin_amdgcn_mfma_i32_16x16x64_i8(bitsel(wn0, t), bf0, acn, 0, 0, 0);
            acn = __builtin_amdgcn_mfma_i32_16x16x64_i8(bitsel(wn1, t), bf1, acn, 0, 0, 0);
            mn = max(max(acn[0], acn[1]), max(max(acn[2], acn[3]), mn));
        }
        #pragma unroll
        for (int off = 32; off > 0; off >>= 1) {
            mp = max(mp, __shfl_xor(mp, off));
            mn = max(mn, __shfl_xor(mn, off));
        }
        if (lane == 0) { smax[wid][sub][0] = (uint32_t)mp; smax[wid][sub][1] = (uint32_t)mn; }
    }
    __syncthreads();
    if (tid < 18) {
        int sub = tid >> 1, sg = tid & 1;
        uint32_t m = 0;
        #pragma unroll
        for (int w2 = 0; w2 < 8; ++w2) m = max(m, smax[w2][sub][sg]);
        atomicMax(&maxv[tid], m);
    }
}

// ---------------------------------------------------------------------------
// f64-exact ADC LUT (tie-exact vs float64 numpy golden).
// ---------------------------------------------------------------------------
__global__ void k_lut(const uint32_t* __restrict__ maxv, uint8_t* __restrict__ lut) {
    int i = threadIdx.x;
    for (int e = i; e < 18 * 129; e += 256) {
        int idx = e / 129, pr = e % 129;
        double vmaxd = fmax((double)maxv[idx], 1e-6);
        double step = vmaxd / 15.0;
        double q = rint((double)pr / step);
        q = fmin(fmax(q, 0.0), 15.0);
        lut[idx * 132 + pr] = (uint8_t)q;
    }
}

// ---------------------------------------------------------------------------
// Pass 2: MFMA pr -> LDS-LUT ADC codes -> exact integer weighted sums
// run = sum_sub (vmax_p*Sp - vmax_n*Sn); 8 s-waves reduced in LDS -> f32 out.
// ---------------------------------------------------------------------------
__global__ __launch_bounds__(512) void k_adc(const uint8_t* __restrict__ xq,
                                             const uint8_t* __restrict__ wqp,
                                             const uint8_t* __restrict__ wqn,
                                             const uint32_t* __restrict__ maxv,
                                             const uint8_t* __restrict__ lut,
                                             const float* __restrict__ norm,
                                             float* __restrict__ out) {
    int tid = threadIdx.x, lane = tid & 63, wid = tid >> 6;
    int blk = blockIdx.x;
    int b = blk >> 9, r = blk & 511, ot = r >> 6, pt = r & 63;
    int s = wid;
    int col = lane & 15, kq = lane >> 4;
    int p = pt * 16 + col, oa = ot * 16 + col;

    __shared__ uint8_t llut[4 * 2376];
    __shared__ int lred[8][64][4];
    {
        const uint32_t* l32 = (const uint32_t*)lut;
        uint32_t* s32 = (uint32_t*)llut;
        for (int i = tid; i < 594; i += 512) {
            uint32_t v = l32[i];
            #pragma unroll
            for (int c2 = 0; c2 < 4; ++c2) s32[c2 * 594 + i] = v;
        }
    }
    __syncthreads();
    const uint8_t* myl = llut + (lane & 3) * 2376;

    const uint8_t* xbase = xq + (size_t)((b << 10) + p) * FTOT + kq * 16;
    const uint8_t* wpb = wqp + (size_t)oa * FTOT + kq * 16;
    const uint8_t* wnb = wqn + (size_t)oa * FTOT + kq * 16;

    int run[4] = {0, 0, 0, 0};
    for (int sub = 0; sub < NSUB; ++sub) {
        int fo = sub * 128;
        uint4 xg0 = *(const uint4*)(xbase + fo);
        uint4 xg1 = *(const uint4*)(xbase + fo + 64);
        v4i bf0 = bitsel(xg0, s), bf1 = bitsel(xg1, s);
        uint4 wp0 = *(const uint4*)(wpb + fo), wp1 = *(const uint4*)(wpb + fo + 64);
        uint4 wn0 = *(const uint4*)(wnb + fo), wn1 = *(const uint4*)(wnb + fo + 64);
        const uint8_t* lp = myl + sub * 264;
        const uint8_t* ln = lp + 132;
        int vp = (int)maxv[sub * 2], vn = (int)maxv[sub * 2 + 1];
        uint32_t Sp[4] = {0, 0, 0, 0}, Sn[4] = {0, 0, 0, 0};
        #pragma unroll
        for (int t = 0; t < NT; ++t) {
            v4i acc = {0, 0, 0, 0};
            acc = __builtin_amdgcn_mfma_i32_16x16x64_i8(bitsel(wp0, t), bf0, acc, 0, 0, 0);
            acc = __builtin_amdgcn_mfma_i32_16x16x64_i8(bitsel(wp1, t), bf1, acc, 0, 0, 0);
            #pragma unroll
            for (int i = 0; i < 4; ++i) Sp[i] += (uint32_t)lp[acc[i]] << (s + t);
            v4i acn = {0, 0, 0, 0};
            acn = __builtin_amdgcn_mfma_i32_16x16x64_i8(bitsel(wn0, t), bf0, acn, 0, 0, 0);
            acn = __builtin_amdgcn_mfma_i32_16x16x64_i8(bitsel(wn1, t), bf1, acn, 0, 0, 0);
            #pragma unroll
            for (int i = 0; i < 4; ++i) Sn[i] += (uint32_t)ln[acn[i]] << (s + t);
        }
        #pragma unroll
        for (int i = 0; i < 4; ++i) run[i] += vp * (int)Sp[i] - vn * (int)Sn[i];
    }
    #pragma unroll
    for (int i = 0; i < 4; ++i) lred[wid][lane][i] = run[i];
    __syncthreads();
    if (tid < 256) {
        int lane2 = tid >> 2, i = tid & 3;
        long long s64 = 0;
        #pragma unroll
        for (int w2 = 0; w2 < 8; ++w2) s64 += (long long)lred[w2][lane2][i];
        int o = ot * 16 + (lane2 >> 4) * 4 + i;      // C/D: row=(lane>>4)*4+reg [m89]
        int pp2 = pt * 16 + (lane2 & 15);            // C/D: col=lane&15
        double v = (double)s64 * (double)norm[o] / 15.0 / 255.0 / 256.0;
        out[((size_t)(b * COUT_ + o)) * PP + pp2] = (float)v;
    }
    if (blk == 0 && tid == 0) out[(size_t)B_ * COUT_ * PP] = 0.0f;   // adc_loss
}

// ---------------------------------------------------------------------------
extern "C" void kernel_launch(void* const* d_in, const int* in_sizes, int n_in,
                              void* d_out, int out_size, void* d_ws, size_t ws_size,
                              hipStream_t stream) {
    const float* x = (const float*)d_in[0];
    const float* w = (const float*)d_in[1];
    float* out = (float*)d_out;
    char* ws = (char*)d_ws;

    float* norm = (float*)(ws + OFF_NORM);
    uint32_t* maxv = (uint32_t*)(ws + OFF_MAXV);
    uint8_t* lut = (uint8_t*)(ws + OFF_LUT);
    uint8_t* wqp = (uint8_t*)(ws + OFF_WQP);
    uint8_t* wqn = (uint8_t*)(ws + OFF_WQN);
    uint8_t* xq  = (uint8_t*)(ws + OFF_XQ);

    hipMemsetAsync(maxv, 0, 18 * sizeof(uint32_t), stream);
    k_prep_w<<<128, 256, 0, stream>>>(w, norm, wqp, wqn);
    k_prep_x<<<576, 256, 0, stream>>>(x, xq);
    k_max<<<1024, 512, 0, stream>>>(xq, wqp, wqn, maxv);
    k_lut<<<1, 256, 0, stream>>>(maxv, lut);
    k_adc<<<1024, 512, 0, stream>>>(xq, wqp, wqn, maxv, lut, norm, out);
}